// Round 7
// baseline (165.259 us; speedup 1.0000x reference)
//
#include <hip/hip_runtime.h>
#include <hip/hip_bf16.h>

#define BSZ 256
#define ADIM 128
#define HID 512
#define MT 64          // pair-rows per block
#define LDH 520        // padded LDS row stride in bf16 elements

typedef __attribute__((ext_vector_type(8))) short short8;
typedef __attribute__((ext_vector_type(4))) float float4_t;
typedef __attribute__((ext_vector_type(16))) float float16_t;
typedef __attribute__((ext_vector_type(4))) unsigned uint4_t;

__device__ inline short f32_to_bf16_bits(float f) {
    union { float f; unsigned u; } v; v.f = f;
    unsigned u = v.u;
    unsigned r = u + 0x7FFFu + ((u >> 16) & 1u);   // RNE
    return (short)(r >> 16);
}

// packed RNE f32x2 -> bf16x2 (no builtin on gfx950; inline asm per guide)
__device__ __forceinline__ unsigned cvt_pk_bf16(float lo, float hi) {
    unsigned r;
    asm("v_cvt_pk_bf16_f32 %0, %1, %2" : "=v"(r) : "v"(lo), "v"(hi));
    return r;
}

// ---------------- prep (256 blocks x 512 threads) ----------------
// blocks [0,64):    hx = x@Wx + b0   (4 rows per block)
// blocks [64,128):  hy = y@Wy        (4 rows per block)
// blocks [128,192): W1p = 32x32-frag-packed bf16 of W1 (64x64 tile per block)
// blocks [192,256): W2p = same for W2
// Packed layout for mfma_f32_32x32x16_bf16 B-fragments:
//   Wp[((s16*16 + g32)*64 + l)*8 + j] = W[s16*16 + (l>>5)*8 + j][g32*32 + (l&31)]
__global__ __launch_bounds__(512) void prep_kernel(
        const float* __restrict__ x, const float* __restrict__ y,
        const float* __restrict__ Wx, const float* __restrict__ Wy,
        const float* __restrict__ b0, const float* __restrict__ W1,
        const float* __restrict__ W2,
        float* __restrict__ hx, float* __restrict__ hy,
        short* __restrict__ W1p, short* __restrict__ W2p) {
    __shared__ float lds[64 * 65];
    const int tid = threadIdx.x;
    const int bid = blockIdx.x;

    if (bid < 128) {
        const bool isX = bid < 64;
        const int i0 = (isX ? bid : bid - 64) * 4;
        const float* src = isX ? x : y;
        const float* W   = isX ? Wx : Wy;
        float* dst       = isX ? hx : hy;

        // x/y row values are wave-uniform -> scalar (SMEM) loads.
        const int h = tid;
        const float* r0 = src + i0 * ADIM;
        float s0 = 0.f, s1 = 0.f, s2 = 0.f, s3 = 0.f;
        const float* wcol = W + h;
        #pragma unroll 8
        for (int k = 0; k < ADIM; ++k) {
            float w = wcol[k * HID];
            s0 = fmaf(r0[k], w, s0);
            s1 = fmaf(r0[ADIM + k], w, s1);
            s2 = fmaf(r0[2 * ADIM + k], w, s2);
            s3 = fmaf(r0[3 * ADIM + k], w, s3);
        }
        float bb = isX ? b0[h] : 0.f;
        dst[(i0 + 0) * HID + h] = s0 + bb;
        dst[(i0 + 1) * HID + h] = s1 + bb;
        dst[(i0 + 2) * HID + h] = s2 + bb;
        dst[(i0 + 3) * HID + h] = s3 + bb;
    } else {
        const int tb = bid - 128;
        const bool is1 = tb < 64;
        const int t8 = is1 ? tb : tb - 64;
        const float* Wsrc = is1 ? W1 : W2;
        short* Wdst = is1 ? W1p : W2p;
        const int k0 = (t8 >> 3) * 64;      // source k block
        const int n0 = (t8 & 7) * 64;       // source n block

        // load + transpose 64x64 f32 tile into LDS: lds[n*65 + k]
        #pragma unroll
        for (int i = 0; i < 8; ++i) {
            int r = (tid >> 6) + i * 8;     // k within tile
            int c = tid & 63;               // n within tile (coalesced)
            lds[c * 65 + r] = Wsrc[(k0 + r) * HID + n0 + c];
        }
        __syncthreads();

        // write 32x32-frag-packed: thread -> one 16B chunk
        const int local_s = tid >> 7;           // 0..3 (k-step of 16 in tile)
        const int g_local = (tid >> 6) & 1;     // 0..1 (n-tile of 32 in tile)
        const int lane    = tid & 63;
        const int half    = lane >> 5;
        const int l31     = lane & 31;
        const int s_glob  = (t8 >> 3) * 4 + local_s;   // 0..31
        const int g_glob  = (t8 & 7) * 2 + g_local;    // 0..15

        const float* srcp = lds + (g_local * 32 + l31) * 65 + local_s * 16 + half * 8;
        short8 v;
        #pragma unroll
        for (int j = 0; j < 8; ++j) v[j] = f32_to_bf16_bits(srcp[j]);
        *(short8*)(Wdst + ((s_glob * 16 + g_glob) * 64 + lane) * 8) = v;
    }
}

// ---------------- fused layer: 8 waves as 2(M) x 4(N) grid ----------------
// Wave (mw, nw) computes rows mw*32..+31, cols nw*128..+127 with 32x32x16
// MFMA. Per K16-step: ONE A ds_read_b128 (halves the block's LDS A-traffic
// vs the 64x64-per-wave split -- the measured CU-level bottleneck), 4
// B-loads from L1/L2 (mw-pair reads duplicate addresses; L1 absorbs).
__device__ __forceinline__ void gemm_layer(short* __restrict__ hs,
                                           const short* __restrict__ Wp,
                                           const float* __restrict__ bias,
                                           int wave, int lane) {
    const int half = lane >> 5;
    const int l31 = lane & 31;
    const int mw = wave >> 2;          // 0..1 : M-half (32 rows)
    const int nw = wave & 3;           // 0..3 : N-quarter (128 cols)
    const int n0 = nw * 128;

    float16_t acc[4];
    #pragma unroll
    for (int ni = 0; ni < 4; ++ni)
        #pragma unroll
        for (int r = 0; r < 16; ++r)
            acc[ni][r] = 0.f;

    // B frag ni: g32 = nw*4 + ni; addr = Wp + ((s*16 + g32)*64 + lane)*8
    const short* pb = Wp + nw * 2048 + lane * 8;       // + ni*512 + s*8192
    const short* abase = hs + (mw * 32 + l31) * LDH + half * 8;   // + s*16

    float bv[4];
    #pragma unroll
    for (int ni = 0; ni < 4; ++ni) bv[ni] = bias[n0 + ni * 32 + l31];

    short8 bf[2][4];
    #pragma unroll
    for (int ni = 0; ni < 4; ++ni)
        bf[0][ni] = *(const short8*)(pb + ni * 512);
    const short* ps = pb + 8192;

    short8 af[2];
    af[0] = *(const short8*)(abase);

    #pragma unroll
    for (int s = 0; s < 32; ++s) {
        const int cur = s & 1;
        if (s < 31) {
            #pragma unroll
            for (int ni = 0; ni < 4; ++ni)
                bf[cur ^ 1][ni] = *(const short8*)(ps + ni * 512);
            ps += 8192;
            af[cur ^ 1] = *(const short8*)(abase + (s + 1) * 16);
        }
        __builtin_amdgcn_s_setprio(1);
        #pragma unroll
        for (int ni = 0; ni < 4; ++ni)
            acc[ni] = __builtin_amdgcn_mfma_f32_32x32x16_bf16(
                af[cur], bf[cur][ni], acc[ni], 0, 0, 0);
        __builtin_amdgcn_s_setprio(0);
    }

    __syncthreads();   // all reads of hs complete before overwrite

    // Epilogue. C/D layout (verified m74/m101): col = l31,
    // row = (reg&3) + 8*(reg>>2) + 4*half (+ mw*32).
    #pragma unroll
    for (int ni = 0; ni < 4; ++ni) {
        unsigned short* wb = (unsigned short*)hs
            + (mw * 32 + 4 * half) * LDH + n0 + ni * 32 + l31;
        #pragma unroll
        for (int rp = 0; rp < 8; ++rp) {
            const int r0 = 2 * rp;
            const int row_off = ((r0 & 3) + 8 * (r0 >> 2)) * LDH;
            float v0 = fmaxf(acc[ni][r0] + bv[ni], 0.f);
            float v1 = fmaxf(acc[ni][r0 + 1] + bv[ni], 0.f);
            unsigned p = cvt_pk_bf16(v0, v1);
            wb[row_off]       = (unsigned short)p;
            wb[row_off + LDH] = (unsigned short)(p >> 16);
        }
    }
    __syncthreads();
}

__global__ __launch_bounds__(512, 4) void critic_kernel(
    const float* __restrict__ hx, const float* __restrict__ hy,
    const short* __restrict__ W1p, const short* __restrict__ W2p,
    const float* __restrict__ b1, const float* __restrict__ b2,
    const float* __restrict__ W3, const float* __restrict__ b3,
    float* __restrict__ out) {
    __shared__ short hs[MT * LDH];   // 66,560 B
    __shared__ float psum[64 * 9];   // 2,304 B -> 2 blocks/CU

    const int tid = threadIdx.x;
    const int wave = tid >> 6;
    const int lane = tid & 63;
    const int quad = lane >> 4;
    const int lq   = lane & 15;

    const int i0 = (blockIdx.x >> 5) * 8;
    const int j0 = (blockIdx.x & 31) * 8;

    // ---- h0 = relu(hx[i] + hy[j]) bf16 in LDS (b0 folded into hx) ----
    #pragma unroll
    for (int e = tid; e < MT * 64; e += 512) {
        int r = e >> 6;
        int ko = (e & 63) * 8;
        int ti = r >> 3, tj = r & 7;
        const float4_t* px = (const float4_t*)(hx + (i0 + ti) * HID + ko);
        const float4_t* py = (const float4_t*)(hy + (j0 + tj) * HID + ko);
        float4_t a0 = px[0], a1 = px[1];
        float4_t c0 = py[0], c1 = py[1];
        unsigned d0 = cvt_pk_bf16(fmaxf(a0[0] + c0[0], 0.f), fmaxf(a0[1] + c0[1], 0.f));
        unsigned d1 = cvt_pk_bf16(fmaxf(a0[2] + c0[2], 0.f), fmaxf(a0[3] + c0[3], 0.f));
        unsigned d2 = cvt_pk_bf16(fmaxf(a1[0] + c1[0], 0.f), fmaxf(a1[1] + c1[1], 0.f));
        unsigned d3 = cvt_pk_bf16(fmaxf(a1[2] + c1[2], 0.f), fmaxf(a1[3] + c1[3], 0.f));
        *(uint4_t*)(hs + r * LDH + ko) = (uint4_t){d0, d1, d2, d3};
    }
    __syncthreads();

    gemm_layer(hs, W1p, b1, wave, lane);   // h1 = relu(h0 @ W1 + b1)
    gemm_layer(hs, W2p, b2, wave, lane);   // h2 = relu(h1 @ W2 + b2)

    // ---- final: out = h2 @ W3 + b3, via 16x16 MFMA (B nonzero only col 0) ----
    {
        const int n0 = wave * 64;
        // B-fragment for k-step s2: B[k = s2*32 + quad*8 + j][col = lq].
        union { unsigned u[4]; short8 v; } w3u[2];
        #pragma unroll
        for (int s2 = 0; s2 < 2; ++s2) {
            float wv[8];
            #pragma unroll
            for (int j = 0; j < 8; ++j)
                wv[j] = (lq == 0) ? W3[n0 + s2 * 32 + quad * 8 + j] : 0.f;
            #pragma unroll
            for (int j = 0; j < 4; ++j)
                w3u[s2].u[j] = cvt_pk_bf16(wv[2 * j], wv[2 * j + 1]);
        }

        float4_t facc[4];
        #pragma unroll
        for (int mi = 0; mi < 4; ++mi) facc[mi] = (float4_t){0.f, 0.f, 0.f, 0.f};

        const short* abase = hs + lq * LDH + n0 + quad * 8;
        #pragma unroll
        for (int s2 = 0; s2 < 2; ++s2)
            #pragma unroll
            for (int mi = 0; mi < 4; ++mi) {
                short8 af = *(const short8*)(abase + mi * 16 * LDH + s2 * 32);
                facc[mi] = __builtin_amdgcn_mfma_f32_16x16x32_bf16(
                    af, w3u[s2].v, facc[mi], 0, 0, 0);
            }

        if (lq == 0) {
            #pragma unroll
            for (int mi = 0; mi < 4; ++mi)
                #pragma unroll
                for (int r = 0; r < 4; ++r)
                    psum[(mi * 16 + quad * 4 + r) * 9 + wave] = facc[mi][r];
        }
    }
    __syncthreads();
    if (tid < 64) {
        float s = b3[0];
        #pragma unroll
        for (int o = 0; o < 8; ++o) s += psum[tid * 9 + o];
        out[(i0 + (tid >> 3)) * BSZ + (j0 + (tid & 7))] = s;
    }
}

extern "C" void kernel_launch(void* const* d_in, const int* in_sizes, int n_in,
                              void* d_out, int out_size, void* d_ws, size_t ws_size,
                              hipStream_t stream) {
    const float* x  = (const float*)d_in[0];
    const float* y  = (const float*)d_in[1];
    const float* Wx = (const float*)d_in[2];
    const float* Wy = (const float*)d_in[3];
    const float* b0 = (const float*)d_in[4];
    const float* W1 = (const float*)d_in[5];
    const float* b1 = (const float*)d_in[6];
    const float* W2 = (const float*)d_in[7];
    const float* b2 = (const float*)d_in[8];
    const float* W3 = (const float*)d_in[9];
    const float* b3 = (const float*)d_in[10];
    float* out = (float*)d_out;

    char* ws = (char*)d_ws;
    float* hx  = (float*)(ws);
    float* hy  = (float*)(ws + 512 * 1024);
    short* W1p = (short*)(ws + 1024 * 1024);
    short* W2p = (short*)(ws + 1536 * 1024);

    prep_kernel<<<256, 512, 0, stream>>>(x, y, Wx, Wy, b0, W1, W2, hx, hy, W1p, W2p);
    critic_kernel<<<1024, 512, 0, stream>>>(hx, hy, W1p, W2p, b1, b2, W3, b3, out);
}

// Round 8
// 141.260 us; speedup vs baseline: 1.1699x; 1.1699x over previous
//
#include <hip/hip_runtime.h>
#include <hip/hip_bf16.h>

#define BSZ 256
#define ADIM 128
#define HID 512
#define MT 128         // pair-rows per block (8 i x 16 j), two 64-row halves
#define LDH 520        // padded LDS row stride in bf16 elements

typedef __attribute__((ext_vector_type(8))) short short8;
typedef __attribute__((ext_vector_type(4))) float float4_t;
typedef __attribute__((ext_vector_type(4))) unsigned uint4_t;

__device__ inline short f32_to_bf16_bits(float f) {
    union { float f; unsigned u; } v; v.f = f;
    unsigned u = v.u;
    unsigned r = u + 0x7FFFu + ((u >> 16) & 1u);   // RNE
    return (short)(r >> 16);
}

// packed RNE f32x2 -> bf16x2 (no builtin on gfx950; inline asm per guide)
__device__ __forceinline__ unsigned cvt_pk_bf16(float lo, float hi) {
    unsigned r;
    asm("v_cvt_pk_bf16_f32 %0, %1, %2" : "=v"(r) : "v"(lo), "v"(hi));
    return r;
}

// ---------------- prep (256 blocks x 512 threads) ----------------
// blocks [0,64):    hx = x@Wx + b0   (4 rows per block)
// blocks [64,128):  hy = y@Wy        (4 rows per block)
// blocks [128,192): W1p = fragment-packed bf16 of W1 (64x64 tile per block)
// blocks [192,256): W2p = fragment-packed bf16 of W2
// Packed layout (16x16x32 B-fragments):
// Wp[((s*32+g)*64 + lane)*8 + j] = W[s*32 + (lane>>4)*8 + j][g*16 + (lane&15)]
__global__ __launch_bounds__(512) void prep_kernel(
        const float* __restrict__ x, const float* __restrict__ y,
        const float* __restrict__ Wx, const float* __restrict__ Wy,
        const float* __restrict__ b0, const float* __restrict__ W1,
        const float* __restrict__ W2,
        float* __restrict__ hx, float* __restrict__ hy,
        short* __restrict__ W1p, short* __restrict__ W2p) {
    __shared__ float lds[64 * 65];
    const int tid = threadIdx.x;
    const int bid = blockIdx.x;

    if (bid < 128) {
        const bool isX = bid < 64;
        const int i0 = (isX ? bid : bid - 64) * 4;
        const float* src = isX ? x : y;
        const float* W   = isX ? Wx : Wy;
        float* dst       = isX ? hx : hy;

        // x/y row values are wave-uniform -> scalar (SMEM) loads.
        const int h = tid;
        const float* r0 = src + i0 * ADIM;
        float s0 = 0.f, s1 = 0.f, s2 = 0.f, s3 = 0.f;
        const float* wcol = W + h;
        #pragma unroll 8
        for (int k = 0; k < ADIM; ++k) {
            float w = wcol[k * HID];
            s0 = fmaf(r0[k], w, s0);
            s1 = fmaf(r0[ADIM + k], w, s1);
            s2 = fmaf(r0[2 * ADIM + k], w, s2);
            s3 = fmaf(r0[3 * ADIM + k], w, s3);
        }
        float bb = isX ? b0[h] : 0.f;
        dst[(i0 + 0) * HID + h] = s0 + bb;
        dst[(i0 + 1) * HID + h] = s1 + bb;
        dst[(i0 + 2) * HID + h] = s2 + bb;
        dst[(i0 + 3) * HID + h] = s3 + bb;
    } else {
        const int tb = bid - 128;
        const bool is1 = tb < 64;
        const int t8 = is1 ? tb : tb - 64;
        const float* Wsrc = is1 ? W1 : W2;
        short* Wdst = is1 ? W1p : W2p;
        const int k0 = (t8 >> 3) * 64;      // source k block
        const int n0 = (t8 & 7) * 64;       // source n block

        // load + transpose 64x64 f32 tile into LDS: lds[n*65 + k]
        #pragma unroll
        for (int i = 0; i < 8; ++i) {
            int r = (tid >> 6) + i * 8;     // k within tile
            int c = tid & 63;               // n within tile (coalesced)
            lds[c * 65 + r] = Wsrc[(k0 + r) * HID + n0 + c];
        }
        __syncthreads();

        // write fragment-packed: thread t -> one 16B chunk
        const int local_s = tid >> 8;           // 0..1
        const int g_local = (tid >> 6) & 3;     // 0..3
        const int lane    = tid & 63;
        const int quad    = lane >> 4;
        const int lq      = lane & 15;
        const int s_glob  = (t8 >> 3) * 2 + local_s;   // 0..15
        const int g_glob  = (t8 & 7) * 4 + g_local;    // 0..31

        const float* srcp = lds + (g_local * 16 + lq) * 65 + local_s * 32 + quad * 8;
        short8 v;
        #pragma unroll
        for (int j = 0; j < 8; ++j) v[j] = f32_to_bf16_bits(srcp[j]);
        *(short8*)(Wdst + ((s_glob * 32 + g_glob) * 64 + lane) * 8) = v;
    }
}

// ---------------- fused layer: wave computes 64(M) x 64(N) chunk ----------------
// Identical to the round-2 winner. hs points at this wave-group's 64-row half.
__device__ __forceinline__ void gemm_layer(short* __restrict__ hs,
                                           const short* __restrict__ Wp,
                                           const float* __restrict__ bias,
                                           int w8, int lane) {
    const int quad = lane >> 4;
    const int lq = lane & 15;
    const int n0 = w8 * 64;

    float4_t acc[4][4];
    #pragma unroll
    for (int mi = 0; mi < 4; ++mi)
        #pragma unroll
        for (int ni = 0; ni < 4; ++ni)
            acc[mi][ni] = (float4_t){0.f, 0.f, 0.f, 0.f};

    const short* pb = Wp + w8 * 2048 + lane * 8;       // + ni*512 + s*16384
    const short* abase = hs + lq * LDH + quad * 8;

    short8 bf[2][4];
    #pragma unroll
    for (int ni = 0; ni < 4; ++ni)
        bf[0][ni] = *(const short8*)(pb + ni * 512);

    // pointer-chained prefetch base: each step's 4 loads use imm offsets
    const short* ps = pb + 16384;

    #pragma unroll
    for (int s = 0; s < 16; ++s) {
        const int cur = s & 1;
        if (s < 15) {
            #pragma unroll
            for (int ni = 0; ni < 4; ++ni)
                bf[cur ^ 1][ni] = *(const short8*)(ps + ni * 512);
            ps += 16384;
        }
        short8 af[4];
        #pragma unroll
        for (int mi = 0; mi < 4; ++mi)
            af[mi] = *(const short8*)(abase + mi * 16 * LDH + s * 32);
        __builtin_amdgcn_s_setprio(1);
        #pragma unroll
        for (int mi = 0; mi < 4; ++mi)
            #pragma unroll
            for (int ni = 0; ni < 4; ++ni)
                acc[mi][ni] = __builtin_amdgcn_mfma_f32_16x16x32_bf16(
                    af[mi], bf[cur][ni], acc[mi][ni], 0, 0, 0);
        __builtin_amdgcn_s_setprio(0);
    }

    float bv[4];
    #pragma unroll
    for (int ni = 0; ni < 4; ++ni) bv[ni] = bias[n0 + ni * 16 + lq];

    __syncthreads();   // all reads of hs complete before overwrite

    // epilogue: bias+relu, packed RNE cvt (2 elems/instr), b16 lo/hi stores
    #pragma unroll
    for (int ni = 0; ni < 4; ++ni) {
        #pragma unroll
        for (int mi = 0; mi < 4; ++mi) {
            float v0 = fmaxf(acc[mi][ni][0] + bv[ni], 0.f);
            float v1 = fmaxf(acc[mi][ni][1] + bv[ni], 0.f);
            float v2 = fmaxf(acc[mi][ni][2] + bv[ni], 0.f);
            float v3 = fmaxf(acc[mi][ni][3] + bv[ni], 0.f);
            unsigned p01 = cvt_pk_bf16(v0, v1);
            unsigned p23 = cvt_pk_bf16(v2, v3);
            unsigned short* wb = (unsigned short*)hs
                + (mi * 16 + quad * 4) * LDH + n0 + ni * 16 + lq;
            wb[0]        = (unsigned short)p01;
            wb[LDH]      = (unsigned short)(p01 >> 16);
            wb[2 * LDH]  = (unsigned short)p23;
            wb[3 * LDH]  = (unsigned short)(p23 >> 16);
        }
    }
    __syncthreads();
}

// 1024-thread block: waves 0-7 process hs rows [0,64) (j-subtile 0),
// waves 8-15 process rows [64,128) (j-subtile 1). Twin waves (w, w+8)
// issue identical B addresses -> trailing twin hits L1; L2 B-traffic
// per output pair is halved vs the 512-thread block.
__global__ __launch_bounds__(1024, 4) void critic_kernel(
    const float* __restrict__ hx, const float* __restrict__ hy,
    const short* __restrict__ W1p, const short* __restrict__ W2p,
    const float* __restrict__ b1, const float* __restrict__ b2,
    const float* __restrict__ W3, const float* __restrict__ b3,
    float* __restrict__ out) {
    __shared__ short hs[MT * LDH];   // 133,120 B
    __shared__ float psum[128 * 9];  // 4,608 B  (total 137,728 -> 1 block/CU)

    const int tid = threadIdx.x;
    const int wave = tid >> 6;
    const int lane = tid & 63;
    const int quad = lane >> 4;
    const int lq   = lane & 15;
    const int grp  = wave >> 3;      // 0..1 : j-subtile
    const int w8   = wave & 7;       // n-slice within group

    const int i0 = (blockIdx.x >> 4) * 8;    // 32 i-tiles
    const int j0 = (blockIdx.x & 15) * 16;   // 16 j-tiles

    short* hsg = hs + grp * 64 * LDH;

    // ---- h0 = relu(hx[i] + hy[j]) bf16 in LDS (b0 folded into hx) ----
    // pair-row r in [0,128): i = i0 + (r>>4), j = j0 + (r&15)
    #pragma unroll
    for (int e = tid; e < MT * 64; e += 1024) {
        int r = e >> 6;
        int ko = (e & 63) * 8;
        int ti = r >> 4, tj = r & 15;
        const float4_t* px = (const float4_t*)(hx + (i0 + ti) * HID + ko);
        const float4_t* py = (const float4_t*)(hy + (j0 + tj) * HID + ko);
        float4_t a0 = px[0], a1 = px[1];
        float4_t c0 = py[0], c1 = py[1];
        unsigned d0 = cvt_pk_bf16(fmaxf(a0[0] + c0[0], 0.f), fmaxf(a0[1] + c0[1], 0.f));
        unsigned d1 = cvt_pk_bf16(fmaxf(a0[2] + c0[2], 0.f), fmaxf(a0[3] + c0[3], 0.f));
        unsigned d2 = cvt_pk_bf16(fmaxf(a1[0] + c1[0], 0.f), fmaxf(a1[1] + c1[1], 0.f));
        unsigned d3 = cvt_pk_bf16(fmaxf(a1[2] + c1[2], 0.f), fmaxf(a1[3] + c1[3], 0.f));
        *(uint4_t*)(hs + r * LDH + ko) = (uint4_t){d0, d1, d2, d3};
    }
    __syncthreads();

    gemm_layer(hsg, W1p, b1, w8, lane);   // h1 = relu(h0 @ W1 + b1)
    gemm_layer(hsg, W2p, b2, w8, lane);   // h2 = relu(h1 @ W2 + b2)

    // ---- final: out = h2 @ W3 + b3, via MFMA (B nonzero only in col 0) ----
    {
        const int n0 = w8 * 64;
        // B-fragment for k-step s2: B[k = s2*32 + quad*8 + j][col = lq].
        union { unsigned u[4]; short8 v; } w3u[2];
        #pragma unroll
        for (int s2 = 0; s2 < 2; ++s2) {
            float wv[8];
            #pragma unroll
            for (int j = 0; j < 8; ++j)
                wv[j] = (lq == 0) ? W3[n0 + s2 * 32 + quad * 8 + j] : 0.f;
            #pragma unroll
            for (int j = 0; j < 4; ++j)
                w3u[s2].u[j] = cvt_pk_bf16(wv[2 * j], wv[2 * j + 1]);
        }

        float4_t facc[4];
        #pragma unroll
        for (int mi = 0; mi < 4; ++mi) facc[mi] = (float4_t){0.f, 0.f, 0.f, 0.f};

        const short* abase = hsg + lq * LDH + n0 + quad * 8;
        #pragma unroll
        for (int s2 = 0; s2 < 2; ++s2)
            #pragma unroll
            for (int mi = 0; mi < 4; ++mi) {
                short8 af = *(const short8*)(abase + mi * 16 * LDH + s2 * 32);
                facc[mi] = __builtin_amdgcn_mfma_f32_16x16x32_bf16(
                    af, w3u[s2].v, facc[mi], 0, 0, 0);
            }

        // C/D: col = lane&15, row = quad*4 + r (+ mi*16). Col-0 lanes hold
        // this wave's partial (sum over its 64 h-cols) for its 64 rows.
        if (lq == 0) {
            #pragma unroll
            for (int mi = 0; mi < 4; ++mi)
                #pragma unroll
                for (int r = 0; r < 4; ++r)
                    psum[(grp * 64 + mi * 16 + quad * 4 + r) * 9 + w8] = facc[mi][r];
        }
    }
    __syncthreads();
    if (tid < 128) {
        float s = b3[0];
        #pragma unroll
        for (int o = 0; o < 8; ++o) s += psum[tid * 9 + o];
        out[(i0 + (tid >> 4)) * BSZ + (j0 + (tid & 15))] = s;
    }
}

extern "C" void kernel_launch(void* const* d_in, const int* in_sizes, int n_in,
                              void* d_out, int out_size, void* d_ws, size_t ws_size,
                              hipStream_t stream) {
    const float* x  = (const float*)d_in[0];
    const float* y  = (const float*)d_in[1];
    const float* Wx = (const float*)d_in[2];
    const float* Wy = (const float*)d_in[3];
    const float* b0 = (const float*)d_in[4];
    const float* W1 = (const float*)d_in[5];
    const float* b1 = (const float*)d_in[6];
    const float* W2 = (const float*)d_in[7];
    const float* b2 = (const float*)d_in[8];
    const float* W3 = (const float*)d_in[9];
    const float* b3 = (const float*)d_in[10];
    float* out = (float*)d_out;

    char* ws = (char*)d_ws;
    float* hx  = (float*)(ws);
    float* hy  = (float*)(ws + 512 * 1024);
    short* W1p = (short*)(ws + 1024 * 1024);
    short* W2p = (short*)(ws + 1536 * 1024);

    prep_kernel<<<256, 512, 0, stream>>>(x, y, Wx, Wy, b0, W1, W2, hx, hy, W1p, W2p);
    critic_kernel<<<512, 1024, 0, stream>>>(hx, hy, W1p, W2p, b1, b2, W3, b3, out);
}

// Round 9
// 141.089 us; speedup vs baseline: 1.1713x; 1.0012x over previous
//
#include <hip/hip_runtime.h>
#include <hip/hip_bf16.h>

#define BSZ 256
#define ADIM 128
#define HID 512
#define MT 64          // pair-rows per block
#define LDH 520        // padded LDS row stride in bf16 elements

typedef __attribute__((ext_vector_type(8))) short short8;
typedef __attribute__((ext_vector_type(4))) float float4_t;
typedef __attribute__((ext_vector_type(4))) unsigned uint4_t;

__device__ inline short f32_to_bf16_bits(float f) {
    union { float f; unsigned u; } v; v.f = f;
    unsigned u = v.u;
    unsigned r = u + 0x7FFFu + ((u >> 16) & 1u);   // RNE
    return (short)(r >> 16);
}

// packed RNE f32x2 -> bf16x2 (no builtin on gfx950; inline asm per guide)
__device__ __forceinline__ unsigned cvt_pk_bf16(float lo, float hi) {
    unsigned r;
    asm("v_cvt_pk_bf16_f32 %0, %1, %2" : "=v"(r) : "v"(lo), "v"(hi));
    return r;
}

// Barrier that drains ONLY lgkmcnt (LDS). All cross-wave state in the critic
// kernel is LDS (hs, psum); global inputs are read-only. Leaving vmcnt
// un-drained lets VGPR-destined B-prefetch loads fly across the barrier
// (__syncthreads would force vmcnt(0)). Single asm block = compiler-level
// memory fence on both sides.
__device__ __forceinline__ void barrier_lgkm() {
    asm volatile("s_waitcnt lgkmcnt(0)\n\ts_barrier" ::: "memory");
}

// ---------------- prep (256 blocks x 512 threads) ----------------
// blocks [0,64):    hx = x@Wx + b0   (4 rows per block)
// blocks [64,128):  hy = y@Wy        (4 rows per block)
// blocks [128,192): W1p = fragment-packed bf16 of W1 (64x64 tile per block)
// blocks [192,256): W2p = fragment-packed bf16 of W2
// Packed layout (16x16x32 B-fragments):
// Wp[((s*32+g)*64 + lane)*8 + j] = W[s*32 + (lane>>4)*8 + j][g*16 + (lane&15)]
__global__ __launch_bounds__(512) void prep_kernel(
        const float* __restrict__ x, const float* __restrict__ y,
        const float* __restrict__ Wx, const float* __restrict__ Wy,
        const float* __restrict__ b0, const float* __restrict__ W1,
        const float* __restrict__ W2,
        float* __restrict__ hx, float* __restrict__ hy,
        short* __restrict__ W1p, short* __restrict__ W2p) {
    __shared__ float lds[64 * 65];
    const int tid = threadIdx.x;
    const int bid = blockIdx.x;

    if (bid < 128) {
        const bool isX = bid < 64;
        const int i0 = (isX ? bid : bid - 64) * 4;
        const float* src = isX ? x : y;
        const float* W   = isX ? Wx : Wy;
        float* dst       = isX ? hx : hy;

        // x/y row values are wave-uniform -> scalar (SMEM) loads.
        const int h = tid;
        const float* r0 = src + i0 * ADIM;
        float s0 = 0.f, s1 = 0.f, s2 = 0.f, s3 = 0.f;
        const float* wcol = W + h;
        #pragma unroll 8
        for (int k = 0; k < ADIM; ++k) {
            float w = wcol[k * HID];
            s0 = fmaf(r0[k], w, s0);
            s1 = fmaf(r0[ADIM + k], w, s1);
            s2 = fmaf(r0[2 * ADIM + k], w, s2);
            s3 = fmaf(r0[3 * ADIM + k], w, s3);
        }
        float bb = isX ? b0[h] : 0.f;
        dst[(i0 + 0) * HID + h] = s0 + bb;
        dst[(i0 + 1) * HID + h] = s1 + bb;
        dst[(i0 + 2) * HID + h] = s2 + bb;
        dst[(i0 + 3) * HID + h] = s3 + bb;
    } else {
        const int tb = bid - 128;
        const bool is1 = tb < 64;
        const int t8 = is1 ? tb : tb - 64;
        const float* Wsrc = is1 ? W1 : W2;
        short* Wdst = is1 ? W1p : W2p;
        const int k0 = (t8 >> 3) * 64;      // source k block
        const int n0 = (t8 & 7) * 64;       // source n block

        // load + transpose 64x64 f32 tile into LDS: lds[n*65 + k]
        #pragma unroll
        for (int i = 0; i < 8; ++i) {
            int r = (tid >> 6) + i * 8;     // k within tile
            int c = tid & 63;               // n within tile (coalesced)
            lds[c * 65 + r] = Wsrc[(k0 + r) * HID + n0 + c];
        }
        __syncthreads();

        // write fragment-packed: thread t -> one 16B chunk
        const int local_s = tid >> 8;           // 0..1
        const int g_local = (tid >> 6) & 3;     // 0..3
        const int lane    = tid & 63;
        const int quad    = lane >> 4;
        const int lq      = lane & 15;
        const int s_glob  = (t8 >> 3) * 2 + local_s;   // 0..15
        const int g_glob  = (t8 & 7) * 4 + g_local;    // 0..31

        const float* srcp = lds + (g_local * 16 + lq) * 65 + local_s * 32 + quad * 8;
        short8 v;
        #pragma unroll
        for (int j = 0; j < 8; ++j) v[j] = f32_to_bf16_bits(srcp[j]);
        *(short8*)(Wdst + ((s_glob * 32 + g_glob) * 64 + lane) * 8) = v;
    }
}

// ---------------- fused layer: wave computes 64(M) x 64(N) chunk ----------------
// Identical to the round-2 winner, plus: bf0 is passed in (prefetched by the
// caller during the previous phase) and the NEXT layer's bf0 is issued at
// K-loop end so it flies across the epilogue barriers (lgkm-only barriers
// keep it in flight).
__device__ __forceinline__ void gemm_layer(short* __restrict__ hs,
                                           const short* __restrict__ Wp,
                                           const float* __restrict__ bias,
                                           int wave, int lane,
                                           short8 bf0[4],
                                           const short* __restrict__ nextWp,
                                           short8 nf[4]) {
    const int quad = lane >> 4;
    const int lq = lane & 15;
    const int n0 = wave * 64;

    float4_t acc[4][4];
    #pragma unroll
    for (int mi = 0; mi < 4; ++mi)
        #pragma unroll
        for (int ni = 0; ni < 4; ++ni)
            acc[mi][ni] = (float4_t){0.f, 0.f, 0.f, 0.f};

    const short* pb = Wp + wave * 2048 + lane * 8;     // + ni*512 + s*16384
    const short* abase = hs + lq * LDH + quad * 8;

    short8 bf[2][4];
    #pragma unroll
    for (int ni = 0; ni < 4; ++ni)
        bf[0][ni] = bf0[ni];

    // pointer-chained prefetch base: each step's 4 loads use imm offsets
    const short* ps = pb + 16384;

    #pragma unroll
    for (int s = 0; s < 16; ++s) {
        const int cur = s & 1;
        if (s < 15) {
            #pragma unroll
            for (int ni = 0; ni < 4; ++ni)
                bf[cur ^ 1][ni] = *(const short8*)(ps + ni * 512);
            ps += 16384;
        }
        short8 af[4];
        #pragma unroll
        for (int mi = 0; mi < 4; ++mi)
            af[mi] = *(const short8*)(abase + mi * 16 * LDH + s * 32);
        __builtin_amdgcn_s_setprio(1);
        #pragma unroll
        for (int mi = 0; mi < 4; ++mi)
            #pragma unroll
            for (int ni = 0; ni < 4; ++ni)
                acc[mi][ni] = __builtin_amdgcn_mfma_f32_16x16x32_bf16(
                    af[mi], bf[cur][ni], acc[mi][ni], 0, 0, 0);
        __builtin_amdgcn_s_setprio(0);
    }

    // Issue next layer's first B-fragments NOW: latency hides under the
    // epilogue and crosses both lgkm-only barriers.
    if (nextWp) {
        const short* pn = nextWp + wave * 2048 + lane * 8;
        #pragma unroll
        for (int ni = 0; ni < 4; ++ni)
            nf[ni] = *(const short8*)(pn + ni * 512);
    }

    float bv[4];
    #pragma unroll
    for (int ni = 0; ni < 4; ++ni) bv[ni] = bias[n0 + ni * 16 + lq];

    barrier_lgkm();   // all reads of hs complete before overwrite

    // epilogue: bias+relu, packed RNE cvt (2 elems/instr), b16 lo/hi stores
    #pragma unroll
    for (int ni = 0; ni < 4; ++ni) {
        #pragma unroll
        for (int mi = 0; mi < 4; ++mi) {
            float v0 = fmaxf(acc[mi][ni][0] + bv[ni], 0.f);
            float v1 = fmaxf(acc[mi][ni][1] + bv[ni], 0.f);
            float v2 = fmaxf(acc[mi][ni][2] + bv[ni], 0.f);
            float v3 = fmaxf(acc[mi][ni][3] + bv[ni], 0.f);
            unsigned p01 = cvt_pk_bf16(v0, v1);
            unsigned p23 = cvt_pk_bf16(v2, v3);
            unsigned short* wb = (unsigned short*)hs
                + (mi * 16 + quad * 4) * LDH + n0 + ni * 16 + lq;
            wb[0]        = (unsigned short)p01;
            wb[LDH]      = (unsigned short)(p01 >> 16);
            wb[2 * LDH]  = (unsigned short)p23;
            wb[3 * LDH]  = (unsigned short)(p23 >> 16);
        }
    }
    barrier_lgkm();
}

__global__ __launch_bounds__(512, 4) void critic_kernel(
    const float* __restrict__ hx, const float* __restrict__ hy,
    const short* __restrict__ W1p, const short* __restrict__ W2p,
    const float* __restrict__ b1, const float* __restrict__ b2,
    const float* __restrict__ W3, const float* __restrict__ b3,
    float* __restrict__ out) {
    __shared__ short hs[MT * LDH];   // 66,560 B
    __shared__ float psum[64 * 9];   // 2,304 B -> 2 blocks/CU

    const int tid = threadIdx.x;
    const int wave = tid >> 6;
    const int lane = tid & 63;
    const int quad = lane >> 4;
    const int lq   = lane & 15;

    const int i0 = (blockIdx.x >> 5) * 8;
    const int j0 = (blockIdx.x & 31) * 8;

    // ---- prefetch layer-1's first B-fragments; latency hides under h0 ----
    short8 nf1[4], nf2[4];
    {
        const short* pb1 = W1p + wave * 2048 + lane * 8;
        #pragma unroll
        for (int ni = 0; ni < 4; ++ni)
            nf1[ni] = *(const short8*)(pb1 + ni * 512);
    }

    // ---- h0 = relu(hx[i] + hy[j]) bf16 in LDS (b0 folded into hx) ----
    #pragma unroll
    for (int e = tid; e < MT * 64; e += 512) {
        int r = e >> 6;
        int ko = (e & 63) * 8;
        int ti = r >> 3, tj = r & 7;
        const float4_t* px = (const float4_t*)(hx + (i0 + ti) * HID + ko);
        const float4_t* py = (const float4_t*)(hy + (j0 + tj) * HID + ko);
        float4_t a0 = px[0], a1 = px[1];
        float4_t c0 = py[0], c1 = py[1];
        unsigned d0 = cvt_pk_bf16(fmaxf(a0[0] + c0[0], 0.f), fmaxf(a0[1] + c0[1], 0.f));
        unsigned d1 = cvt_pk_bf16(fmaxf(a0[2] + c0[2], 0.f), fmaxf(a0[3] + c0[3], 0.f));
        unsigned d2 = cvt_pk_bf16(fmaxf(a1[0] + c1[0], 0.f), fmaxf(a1[1] + c1[1], 0.f));
        unsigned d3 = cvt_pk_bf16(fmaxf(a1[2] + c1[2], 0.f), fmaxf(a1[3] + c1[3], 0.f));
        *(uint4_t*)(hs + r * LDH + ko) = (uint4_t){d0, d1, d2, d3};
    }
    barrier_lgkm();

    gemm_layer(hs, W1p, b1, wave, lane, nf1, W2p, nf2);     // h1
    gemm_layer(hs, W2p, b2, wave, lane, nf2, nullptr, nf1); // h2

    // ---- final: out = h2 @ W3 + b3, via MFMA (B nonzero only in col 0) ----
    {
        const int n0 = wave * 64;
        // B-fragment for k-step s2: B[k = s2*32 + quad*8 + j][col = lq].
        union { unsigned u[4]; short8 v; } w3u[2];
        #pragma unroll
        for (int s2 = 0; s2 < 2; ++s2) {
            float wv[8];
            #pragma unroll
            for (int j = 0; j < 8; ++j)
                wv[j] = (lq == 0) ? W3[n0 + s2 * 32 + quad * 8 + j] : 0.f;
            #pragma unroll
            for (int j = 0; j < 4; ++j)
                w3u[s2].u[j] = cvt_pk_bf16(wv[2 * j], wv[2 * j + 1]);
        }

        float4_t facc[4];
        #pragma unroll
        for (int mi = 0; mi < 4; ++mi) facc[mi] = (float4_t){0.f, 0.f, 0.f, 0.f};

        const short* abase = hs + lq * LDH + n0 + quad * 8;
        #pragma unroll
        for (int s2 = 0; s2 < 2; ++s2)
            #pragma unroll
            for (int mi = 0; mi < 4; ++mi) {
                short8 af = *(const short8*)(abase + mi * 16 * LDH + s2 * 32);
                facc[mi] = __builtin_amdgcn_mfma_f32_16x16x32_bf16(
                    af, w3u[s2].v, facc[mi], 0, 0, 0);
            }

        // C/D: col = lane&15, row = quad*4 + r (+ mi*16). Col-0 lanes hold
        // this wave's partial (sum over its 64 h-cols) for all 64 rows.
        if (lq == 0) {
            #pragma unroll
            for (int mi = 0; mi < 4; ++mi)
                #pragma unroll
                for (int r = 0; r < 4; ++r)
                    psum[(mi * 16 + quad * 4 + r) * 9 + wave] = facc[mi][r];
        }
    }
    barrier_lgkm();
    if (tid < 64) {
        float s = b3[0];
        #pragma unroll
        for (int o = 0; o < 8; ++o) s += psum[tid * 9 + o];
        out[(i0 + (tid >> 3)) * BSZ + (j0 + (tid & 7))] = s;
    }
}

extern "C" void kernel_launch(void* const* d_in, const int* in_sizes, int n_in,
                              void* d_out, int out_size, void* d_ws, size_t ws_size,
                              hipStream_t stream) {
    const float* x  = (const float*)d_in[0];
    const float* y  = (const float*)d_in[1];
    const float* Wx = (const float*)d_in[2];
    const float* Wy = (const float*)d_in[3];
    const float* b0 = (const float*)d_in[4];
    const float* W1 = (const float*)d_in[5];
    const float* b1 = (const float*)d_in[6];
    const float* W2 = (const float*)d_in[7];
    const float* b2 = (const float*)d_in[8];
    const float* W3 = (const float*)d_in[9];
    const float* b3 = (const float*)d_in[10];
    float* out = (float*)d_out;

    char* ws = (char*)d_ws;
    float* hx  = (float*)(ws);
    float* hy  = (float*)(ws + 512 * 1024);
    short* W1p = (short*)(ws + 1024 * 1024);
    short* W2p = (short*)(ws + 1536 * 1024);

    prep_kernel<<<256, 512, 0, stream>>>(x, y, Wx, Wy, b0, W1, W2, hx, hy, W1p, W2p);
    critic_kernel<<<1024, 512, 0, stream>>>(hx, hy, W1p, W2p, b1, b2, W3, b3, out);
}